// Round 2
// baseline (348.157 us; speedup 1.0000x reference)
//
#include <hip/hip_runtime.h>

#define THRESH 1.0f

// clang native vector type — __builtin_nontemporal_store accepts this,
// unlike HIP_vector_type<float,4>. Same 16-B layout as float4.
typedef float nfloat4 __attribute__((ext_vector_type(4)));

__device__ __forceinline__ float sqdiff4(float4 a, float4 b) {
  float dx = a.x - b.x, dy = a.y - b.y, dz = a.z - b.z, dw = a.w - b.w;
  return dx * dx + dy * dy + dz * dz + dw * dw;
}

// ---------------------------------------------------------------------------
// Kernel 1 (fused edge-flags + mask): one block per cell n = i*32+j.
// Interior cells load their row plus the 4 neighbor rows, compute the four
// edge sum-of-squares (sqrt(s)>1 <=> s>1), OR across batches with early exit.
// Border cells write mask=0 immediately. With random data every edge exceeds
// at b=0, so the batch loop runs once; worst case (adversarial) runs 64x.
// ---------------------------------------------------------------------------
__global__ __launch_bounds__(192) void mask_kernel(
    const float* __restrict__ x, int* __restrict__ mask) {
  const int n = blockIdx.x;
  const int i = n >> 5, j = n & 31;
  const int t = threadIdx.x;
  if (i < 1 || i > 30 || j < 1 || j > 30) {
    if (t == 0) mask[n] = 0;
    return;
  }
  __shared__ float red[3][4];
  __shared__ int sdone;
  if (t == 0) sdone = 0;
  __syncthreads();
  const int lane = t & 63;
  const int wid = t >> 6;
  const float4* xv = (const float4*)x;

  for (int b = 0; b < 64; ++b) {
    const size_t base = ((size_t)b * 1024 + n) * 192 + t;  // float4 units
    float4 c = xv[base];
    float4 l = xv[base - 192];
    float4 r = xv[base + 192];
    float4 u = xv[base - 32 * 192];
    float4 d = xv[base + 32 * 192];
    float sl = sqdiff4(c, l);
    float sr = sqdiff4(r, c);
    float su = sqdiff4(c, u);
    float sd = sqdiff4(d, c);
#pragma unroll
    for (int off = 32; off > 0; off >>= 1) {
      sl += __shfl_down(sl, off, 64);
      sr += __shfl_down(sr, off, 64);
      su += __shfl_down(su, off, 64);
      sd += __shfl_down(sd, off, 64);
    }
    if (lane == 0) {
      red[wid][0] = sl; red[wid][1] = sr;
      red[wid][2] = su; red[wid][3] = sd;
    }
    __syncthreads();
    if (t == 0) {
      float L = red[0][0] + red[1][0] + red[2][0];
      float R = red[0][1] + red[1][1] + red[2][1];
      float U = red[0][2] + red[1][2] + red[2][2];
      float D = red[0][3] + red[1][3] + red[2][3];
      if (L > THRESH || R > THRESH || U > THRESH || D > THRESH) sdone = 1;
    }
    __syncthreads();
    if (sdone) break;  // uniform across block (shared var)
  }
  if (t == 0) mask[n] = sdone;
}

// ---------------------------------------------------------------------------
// Kernel 2: apply. One block per (b, n); 192 lanes = 192 float4 = 768 floats.
// XCD-contiguous swizzle: dispatch round-robins blocks over 8 XCDs, so map
// dispatch index `orig` -> bn = (orig&7)*8192 + (orig>>3). Each XCD then
// walks 8 whole batch-images sequentially; the neighbor-reuse window
// (+-32 rows = ~192 KB) stays resident in that XCD's 4 MB L2, so each x row
// is fetched from HBM exactly once. Output is a pure stream -> nontemporal.
// ---------------------------------------------------------------------------
__global__ __launch_bounds__(192) void apply_kernel(
    const float* __restrict__ x, const int* __restrict__ mask,
    float* __restrict__ out) {
  const int orig = blockIdx.x;
  const int bn = (orig & 7) * 8192 + (orig >> 3);  // 65536 blocks, 8 chunks
  const int n = bn & 1023;
  const int t = threadIdx.x;
  const size_t base = (size_t)bn * 192 + t;
  const float4* xv = (const float4*)x;
  nfloat4* ov = (nfloat4*)out;

  float4 c = xv[base];
  float4 res = c;
  if (mask[n]) {
    float4 l = xv[base - 192];
    float4 r = xv[base + 192];
    float4 u = xv[base - 32 * 192];
    float4 d = xv[base + 32 * 192];
    res.x = 0.5f * c.x + 0.125f * ((l.x + r.x) + (u.x + d.x));
    res.y = 0.5f * c.y + 0.125f * ((l.y + r.y) + (u.y + d.y));
    res.z = 0.5f * c.z + 0.125f * ((l.z + r.z) + (u.z + d.z));
    res.w = 0.5f * c.w + 0.125f * ((l.w + r.w) + (u.w + d.w));
  }
  nfloat4 nres = {res.x, res.y, res.z, res.w};
  __builtin_nontemporal_store(nres, ov + base);
}

extern "C" void kernel_launch(void* const* d_in, const int* in_sizes, int n_in,
                              void* d_out, int out_size, void* d_ws,
                              size_t ws_size, hipStream_t stream) {
  const float* x = (const float*)d_in[0];
  float* out = (float*)d_out;
  int* mask = (int*)d_ws;  // 1024 ints; single-writer per entry, no init

  mask_kernel<<<1024, 192, 0, stream>>>(x, mask);
  apply_kernel<<<64 * 1024, 192, 0, stream>>>(x, mask, out);
}

// Round 3
// 346.428 us; speedup vs baseline: 1.0050x; 1.0050x over previous
//
#include <hip/hip_runtime.h>

#define THRESH 1.0f

// clang native vector type — __builtin_nontemporal_store accepts this.
typedef float nfloat4 __attribute__((ext_vector_type(4)));

__device__ __forceinline__ float sqdiff4(float4 a, float4 b) {
  float dx = a.x - b.x, dy = a.y - b.y, dz = a.z - b.z, dw = a.w - b.w;
  return dx * dx + dy * dy + dz * dz + dw * dw;
}

__device__ __forceinline__ nfloat4 to_n(float4 v) {
  nfloat4 r = {v.x, v.y, v.z, v.w};
  return r;
}

// ---------------------------------------------------------------------------
// Kernel 1 (fused edge-flags + mask): one block per cell n = i*32+j.
// Interior cells load their row plus the 4 neighbor rows, compute the four
// edge sum-of-squares (sqrt(s)>1 <=> s>1), OR across batches with early exit.
// With random data every edge exceeds at b=0, so the batch loop runs once.
// Verified correct in round 2; ~5-10 us.
// ---------------------------------------------------------------------------
__global__ __launch_bounds__(192) void mask_kernel(
    const float* __restrict__ x, int* __restrict__ mask) {
  const int n = blockIdx.x;
  const int i = n >> 5, j = n & 31;
  const int t = threadIdx.x;
  if (i < 1 || i > 30 || j < 1 || j > 30) {
    if (t == 0) mask[n] = 0;
    return;
  }
  __shared__ float red[3][4];
  __shared__ int sdone;
  if (t == 0) sdone = 0;
  __syncthreads();
  const int lane = t & 63;
  const int wid = t >> 6;
  const float4* xv = (const float4*)x;

  for (int b = 0; b < 64; ++b) {
    const size_t base = ((size_t)b * 1024 + n) * 192 + t;  // float4 units
    float4 c = xv[base];
    float4 l = xv[base - 192];
    float4 r = xv[base + 192];
    float4 u = xv[base - 32 * 192];
    float4 d = xv[base + 32 * 192];
    float sl = sqdiff4(c, l);
    float sr = sqdiff4(r, c);
    float su = sqdiff4(c, u);
    float sd = sqdiff4(d, c);
#pragma unroll
    for (int off = 32; off > 0; off >>= 1) {
      sl += __shfl_down(sl, off, 64);
      sr += __shfl_down(sr, off, 64);
      su += __shfl_down(su, off, 64);
      sd += __shfl_down(sd, off, 64);
    }
    if (lane == 0) {
      red[wid][0] = sl; red[wid][1] = sr;
      red[wid][2] = su; red[wid][3] = sd;
    }
    __syncthreads();
    if (t == 0) {
      float L = red[0][0] + red[1][0] + red[2][0];
      float R = red[0][1] + red[1][1] + red[2][1];
      float U = red[0][2] + red[1][2] + red[2][2];
      float D = red[0][3] + red[1][3] + red[2][3];
      if (L > THRESH || R > THRESH || U > THRESH || D > THRESH) sdone = 1;
    }
    __syncthreads();
    if (sdone) break;  // uniform across block (shared var)
  }
  if (t == 0) mask[n] = sdone;
}

// ---------------------------------------------------------------------------
// Kernel 2: stencil-walk apply. One block per (batch, j-group of 8 cells);
// 512 threads: cell cl = t>>6 (8 cells), lane k = t&63, 3 float4 per thread
// per row (k, k+64, k+128). The block walks i = 0..31 keeping rows i-1, i,
// i+1 in registers; the current row (8 own cells + 2 halo cells = 30 KB) is
// staged in LDS for left/right neighbor access. Row i+2 and halo(i+1) are
// prefetched one iteration ahead, so each iteration's loads hide under the
// previous iteration's compute. Each x element is read ONCE (+1.25x j-halo):
// traffic 442 MB total vs 1.09 GB for the per-row gather version (which ran
// at 8.9 TB/s of L1-level traffic -> cache-amplification-bound at 122 us).
// XCD-contiguous swizzle keeps halo-sharing blocks (same b, adjacent jg) on
// the same XCD's L2.
// ---------------------------------------------------------------------------
__global__ __launch_bounds__(512) void apply_kernel(
    const float* __restrict__ x, const int* __restrict__ mask,
    float* __restrict__ out) {
  const int orig = blockIdx.x;          // 256 blocks
  const int bn = (orig & 7) * 32 + (orig >> 3);  // XCD d owns bn d*32..d*32+31
  const int b  = bn >> 2;               // batch 0..63
  const int jg = bn & 3;                // j-group 0..3
  const int t  = threadIdx.x;
  const int cl = t >> 6;                // own cell 0..7
  const int k  = t & 63;
  const int jglob = jg * 8 + cl;

  // staged row: [halo_l | own 0..7 | halo_r], 10 cells x 192 float4 = 30 KB
  __shared__ float4 row[10 * 192];

  const float4* xv = (const float4*)x;
  nfloat4* ov = (nfloat4*)out;

  const size_t batch_base = (size_t)b * 1024 * 192;  // float4 units
  // halo cells (clamped at grid edge; clamped data is never used because
  // border cells have mask=0, but keeps addresses in-bounds)
  const int jL = (jg == 0) ? 0 : jg * 8 - 1;
  const int jR = (jg == 3) ? 31 : jg * 8 + 8;
  const bool haloT = (t < 384);
  const int hj   = (t < 192) ? jL : jR;
  const int hoff = (t < 192) ? t : (t - 192);      // float4 index in cell
  const int hslot = (t < 192) ? hoff : (9 * 192 + hoff);

  float4 rU0, rU1, rU2, rC0, rC1, rC2, rD0, rD1, rD2, rN0, rN1, rN2;
  float4 hC = {0, 0, 0, 0}, hN = {0, 0, 0, 0};

  // row base in float4 units for this thread's own cell
  auto rowbase = [&](int i) -> size_t {
    return batch_base + (size_t)(i * 32 + jglob) * 192 + k;
  };
  auto halobase = [&](int i) -> size_t {
    return batch_base + (size_t)(i * 32 + hj) * 192 + hoff;
  };

  // ---- prologue: rows 0,1,2 + halo(1); out row 0 is a pure copy (mask=0)
  {
    const size_t b0 = rowbase(0), b1 = rowbase(1), b2 = rowbase(2);
    rU0 = xv[b0]; rU1 = xv[b0 + 64]; rU2 = xv[b0 + 128];
    rC0 = xv[b1]; rC1 = xv[b1 + 64]; rC2 = xv[b1 + 128];
    rD0 = xv[b2]; rD1 = xv[b2 + 64]; rD2 = xv[b2 + 128];
    if (haloT) hC = xv[halobase(1)];
    __builtin_nontemporal_store(to_n(rU0), ov + b0);
    __builtin_nontemporal_store(to_n(rU1), ov + b0 + 64);
    __builtin_nontemporal_store(to_n(rU2), ov + b0 + 128);
  }

  // ---- main walk: compute out rows 1..30
  for (int i = 1; i <= 30; ++i) {
    // prefetch for NEXT iteration (row i+2 slices, halo row i+1)
    if (i <= 29) {
      const size_t bnx = rowbase(i + 2);
      rN0 = xv[bnx]; rN1 = xv[bnx + 64]; rN2 = xv[bnx + 128];
      if (haloT) hN = xv[halobase(i + 1)];
    }
    __syncthreads();  // previous iteration's LDS reads complete
    // stage row i (own cells from regs, halo from prefetched hC)
    row[(cl + 1) * 192 + k]       = rC0;
    row[(cl + 1) * 192 + 64 + k]  = rC1;
    row[(cl + 1) * 192 + 128 + k] = rC2;
    if (haloT) row[hslot] = hC;
    __syncthreads();

    const int mv = mask[i * 32 + jglob];  // wave-uniform (64 lanes = 1 cell)
    const size_t ob = rowbase(i);
    float4 res0 = rC0, res1 = rC1, res2 = rC2;
    if (mv) {
      const float4 l0 = row[cl * 192 + k];
      const float4 l1 = row[cl * 192 + 64 + k];
      const float4 l2 = row[cl * 192 + 128 + k];
      const float4 r0 = row[(cl + 2) * 192 + k];
      const float4 r1 = row[(cl + 2) * 192 + 64 + k];
      const float4 r2 = row[(cl + 2) * 192 + 128 + k];
      res0.x = 0.5f * rC0.x + 0.125f * ((l0.x + r0.x) + (rU0.x + rD0.x));
      res0.y = 0.5f * rC0.y + 0.125f * ((l0.y + r0.y) + (rU0.y + rD0.y));
      res0.z = 0.5f * rC0.z + 0.125f * ((l0.z + r0.z) + (rU0.z + rD0.z));
      res0.w = 0.5f * rC0.w + 0.125f * ((l0.w + r0.w) + (rU0.w + rD0.w));
      res1.x = 0.5f * rC1.x + 0.125f * ((l1.x + r1.x) + (rU1.x + rD1.x));
      res1.y = 0.5f * rC1.y + 0.125f * ((l1.y + r1.y) + (rU1.y + rD1.y));
      res1.z = 0.5f * rC1.z + 0.125f * ((l1.z + r1.z) + (rU1.z + rD1.z));
      res1.w = 0.5f * rC1.w + 0.125f * ((l1.w + r1.w) + (rU1.w + rD1.w));
      res2.x = 0.5f * rC2.x + 0.125f * ((l2.x + r2.x) + (rU2.x + rD2.x));
      res2.y = 0.5f * rC2.y + 0.125f * ((l2.y + r2.y) + (rU2.y + rD2.y));
      res2.z = 0.5f * rC2.z + 0.125f * ((l2.z + r2.z) + (rU2.z + rD2.z));
      res2.w = 0.5f * rC2.w + 0.125f * ((l2.w + r2.w) + (rU2.w + rD2.w));
    }
    __builtin_nontemporal_store(to_n(res0), ov + ob);
    __builtin_nontemporal_store(to_n(res1), ov + ob + 64);
    __builtin_nontemporal_store(to_n(res2), ov + ob + 128);

    // shift the register window
    rU0 = rC0; rU1 = rC1; rU2 = rC2;
    rC0 = rD0; rC1 = rD1; rC2 = rD2;
    rD0 = rN0; rD1 = rN1; rD2 = rN2;
    hC = hN;
  }

  // ---- epilogue: out row 31 is a pure copy (rC now holds row 31)
  {
    const size_t b31 = rowbase(31);
    __builtin_nontemporal_store(to_n(rC0), ov + b31);
    __builtin_nontemporal_store(to_n(rC1), ov + b31 + 64);
    __builtin_nontemporal_store(to_n(rC2), ov + b31 + 128);
  }
}

extern "C" void kernel_launch(void* const* d_in, const int* in_sizes, int n_in,
                              void* d_out, int out_size, void* d_ws,
                              size_t ws_size, hipStream_t stream) {
  const float* x = (const float*)d_in[0];
  float* out = (float*)d_out;
  int* mask = (int*)d_ws;  // 1024 ints; single-writer per entry, no init

  mask_kernel<<<1024, 192, 0, stream>>>(x, mask);
  apply_kernel<<<256, 512, 0, stream>>>(x, mask, out);
}

// Round 5
// 340.839 us; speedup vs baseline: 1.0215x; 1.0164x over previous
//
#include <hip/hip_runtime.h>

#define THRESH 1.0f

// clang native vector type — __builtin_nontemporal_store accepts this.
typedef float nfloat4 __attribute__((ext_vector_type(4)));

__device__ __forceinline__ float sqdiff4(float4 a, float4 b) {
  float dx = a.x - b.x, dy = a.y - b.y, dz = a.z - b.z, dw = a.w - b.w;
  return dx * dx + dy * dy + dz * dz + dw * dw;
}

__device__ __forceinline__ nfloat4 to_n(float4 v) {
  nfloat4 r = {v.x, v.y, v.z, v.w};
  return r;
}

// ---------------------------------------------------------------------------
// Kernel 1 (fused edge-flags + mask): one block per cell n = i*32+j.
// Interior cells load their row plus the 4 neighbor rows, compute the four
// edge sum-of-squares (sqrt(s)>1 <=> s>1), OR across batches with early exit.
// With random data every edge exceeds at b=0, so the batch loop runs once.
// Verified correct in rounds 2-3; small vs apply.
// ---------------------------------------------------------------------------
__global__ __launch_bounds__(192) void mask_kernel(
    const float* __restrict__ x, int* __restrict__ mask) {
  const int n = blockIdx.x;
  const int i = n >> 5, j = n & 31;
  const int t = threadIdx.x;
  if (i < 1 || i > 30 || j < 1 || j > 30) {
    if (t == 0) mask[n] = 0;
    return;
  }
  __shared__ float red[3][4];
  __shared__ int sdone;
  if (t == 0) sdone = 0;
  __syncthreads();
  const int lane = t & 63;
  const int wid = t >> 6;
  const float4* xv = (const float4*)x;

  for (int b = 0; b < 64; ++b) {
    const size_t base = ((size_t)b * 1024 + n) * 192 + t;  // float4 units
    float4 c = xv[base];
    float4 l = xv[base - 192];
    float4 r = xv[base + 192];
    float4 u = xv[base - 32 * 192];
    float4 d = xv[base + 32 * 192];
    float sl = sqdiff4(c, l);
    float sr = sqdiff4(r, c);
    float su = sqdiff4(c, u);
    float sd = sqdiff4(d, c);
#pragma unroll
    for (int off = 32; off > 0; off >>= 1) {
      sl += __shfl_down(sl, off, 64);
      sr += __shfl_down(sr, off, 64);
      su += __shfl_down(su, off, 64);
      sd += __shfl_down(sd, off, 64);
    }
    if (lane == 0) {
      red[wid][0] = sl; red[wid][1] = sr;
      red[wid][2] = su; red[wid][3] = sd;
    }
    __syncthreads();
    if (t == 0) {
      float L = red[0][0] + red[1][0] + red[2][0];
      float R = red[0][1] + red[1][1] + red[2][1];
      float U = red[0][2] + red[1][2] + red[2][2];
      float D = red[0][3] + red[1][3] + red[2][3];
      if (L > THRESH || R > THRESH || U > THRESH || D > THRESH) sdone = 1;
    }
    __syncthreads();
    if (sdone) break;  // uniform across block (shared var)
  }
  if (t == 0) mask[n] = sdone;
}

// ---------------------------------------------------------------------------
// Kernel 2: MLP-maximized apply. 192 threads x 4 rows per block.
// Rounds 2-3 post-mortem: both prior versions were LATENCY-bound —
// round 2 by the serial chain (mask load -> branch -> 5 loads) per short-
// lived block; round 3 by 1-block/CU occupancy + syncthreads-serialized
// walk. Fix: all loads UNCONDITIONAL (clamped block-uniform offsets, no
// branch gates them), 20 independent float4 loads in flight per thread,
// mask applied as a select after the loads return. Border rows clamp their
// OOB neighbor to themselves; harmless since mask=0 selects the copy.
// Grid 16384 blocks, XCD-chunked swizzle so u/d rows (+-8 block positions)
// are L2-resident on the same XCD. NT stores keep the write stream out of
// the caches that hold x.
// ---------------------------------------------------------------------------
__global__ __launch_bounds__(192) void apply_kernel(
    const float* __restrict__ x, const int* __restrict__ mask,
    float* __restrict__ out) {
  const int orig = blockIdx.x;                    // 16384 blocks
  const int blk = (orig & 7) * 2048 + (orig >> 3);  // XCD-contiguous chunks
  const int b = blk >> 8;                         // batch 0..63
  const int n0 = (blk & 255) * 4;                 // first row-of-cells
  const int t = threadIdx.x;                      // float4 index in row
  const float4* xv = (const float4*)x;
  nfloat4* ov = (nfloat4*)out;
  const size_t base = ((size_t)b * 1024 + n0) * 192 + t;

  float4 c[4], l[4], r[4], u[4], d[4];
  int mv[4];
#pragma unroll
  for (int s = 0; s < 4; ++s) {
    const int n = n0 + s;
    const int i = n >> 5, j = n & 31;             // block-uniform
    const size_t rb = base + (size_t)(s * 192);
    c[s] = xv[rb];
    l[s] = xv[rb - (j > 0 ? 192 : 0)];
    r[s] = xv[rb + (j < 31 ? 192 : 0)];
    u[s] = xv[rb - (i > 0 ? 32 * 192 : 0)];
    d[s] = xv[rb + (i < 31 ? 32 * 192 : 0)];
    mv[s] = mask[n];
  }
#pragma unroll
  for (int s = 0; s < 4; ++s) {
    float4 res;
    res.x = 0.5f * c[s].x + 0.125f * ((l[s].x + r[s].x) + (u[s].x + d[s].x));
    res.y = 0.5f * c[s].y + 0.125f * ((l[s].y + r[s].y) + (u[s].y + d[s].y));
    res.z = 0.5f * c[s].z + 0.125f * ((l[s].z + r[s].z) + (u[s].z + d[s].z));
    res.w = 0.5f * c[s].w + 0.125f * ((l[s].w + r[s].w) + (u[s].w + d[s].w));
    if (!mv[s]) res = c[s];
    __builtin_nontemporal_store(to_n(res), ov + base + (size_t)(s * 192));
  }
}

extern "C" void kernel_launch(void* const* d_in, const int* in_sizes, int n_in,
                              void* d_out, int out_size, void* d_ws,
                              size_t ws_size, hipStream_t stream) {
  const float* x = (const float*)d_in[0];
  float* out = (float*)d_out;
  int* mask = (int*)d_ws;  // 1024 ints; single-writer per entry, no init

  mask_kernel<<<1024, 192, 0, stream>>>(x, mask);
  apply_kernel<<<16384, 192, 0, stream>>>(x, mask, out);
}